// Round 5
// baseline (207.896 us; speedup 1.0000x reference)
//
#include <hip/hip_runtime.h>

// 2-layer tanh RNN, fused, f32, single-wave blocks, zero global ops in loop.
// B=4096 chains, T=512 steps, H=20.
// KEY CHANGE (R5): each lane owns TWO adjacent output rows (2jj, 2jj+1) of
// ONE batch -> 10 lanes/batch, GB=6 batches/wave. The 10 ds_read_b128 of
// h-state per wave-iter now feed 6 batches (was 3) => LDS-pipe cycles per
// CU per iter halve (R4 model: LDS pipe is the bottleneck, ~12cyc/b128).
// xs rows padded to 516 floats (was stride 512 = 3-way same-bank conflict,
// the 1.4M SQ_LDS_BANK_CONFLICT seen in R3/R4).

#define Bsz 4096
#define Tn  512
#define Hn  20
#define GB  6                  // batches per wave
#define LPB 10                 // lanes per batch (2 output rows each)
#define XPAD 516               // xs row stride: 516%32=4 banks apart per row
#define NTHREADS 64

__device__ __forceinline__ float tanh_fast(float v) {
    // tanh(v) = 1 - 2/(exp(2v)+1); v_exp_f32 + v_rcp_f32.
    float e = __expf(2.0f * v);
    return 1.0f - 2.0f * __builtin_amdgcn_rcpf(e + 1.0f);
}

__global__ __launch_bounds__(NTHREADS, 1)
void rnn2_fused(const float* __restrict__ x,        // [B,T,1]
                const float* __restrict__ hidden,   // [2,B,H]
                const float* __restrict__ W_ih0,    // [H,1]
                const float* __restrict__ W_hh0,    // [H,H]
                const float* __restrict__ b_ih0,    // [H]
                const float* __restrict__ b_hh0,    // [H]
                const float* __restrict__ W_ih1,    // [H,H]
                const float* __restrict__ W_hh1,    // [H,H]
                const float* __restrict__ b_ih1,    // [H]
                const float* __restrict__ b_hh1,    // [H]
                const float* __restrict__ fc_w,     // [1,H]
                const float* __restrict__ fc_b,     // [1]
                float* __restrict__ out)            // [B] ++ [2,B,H] flat
{
    const int tid = threadIdx.x;
    int g  = tid / LPB;                // 0..6
    int jj = tid - g * LPB;            // 0..9
    if (g >= GB) { g = GB - 1; jj = tid - 60; }   // lanes 60..63 dup (5,0..3)
    const int j0 = 2 * jj;             // my even output row (j0, j0+1)

    const int  b        = blockIdx.x * GB + g;
    const bool b_ok     = (b < Bsz);
    const int  bl       = b_ok ? b : (Bsz - 1);
    const bool store_ok = (tid < GB * LPB) && b_ok;

    __shared__ float xs[GB][XPAD];     // ~12.1 KB
    __shared__ float h0s[2][GB][Hn];   // double-buffered hidden state
    __shared__ float h1s[2][GB][Hn];

    // stage ALL x up front (coalesced float4; clamp batch index for safety)
    {
        const int bB = blockIdx.x * GB;
        #pragma unroll
        for (int r = 0; r < (GB * Tn) / (NTHREADS * 4); ++r) {  // 12 rounds
            const int c  = (r * NTHREADS + tid) * 4;
            const int gg = c >> 9;            // c / 512
            const int t  = c & (Tn - 1);      // c % 512
            const int bb = (bB + gg < Bsz) ? (bB + gg) : (Bsz - 1);
            float4 v = *(const float4*)(x + (long)bb * Tn + t);
            *(float4*)&xs[gg][t] = v;
        }
    }

    // per-lane weights: rows j0 and j0+1 of the 3 H x H matrices (120 VGPRs)
    float w0e[Hn], w0o[Hn], w1e[Hn], w1o[Hn], w2e[Hn], w2o[Hn];
    {
        const float4* p0e = (const float4*)(W_hh0 + j0 * Hn);
        const float4* p0o = (const float4*)(W_hh0 + (j0 + 1) * Hn);
        const float4* p1e = (const float4*)(W_ih1 + j0 * Hn);
        const float4* p1o = (const float4*)(W_ih1 + (j0 + 1) * Hn);
        const float4* p2e = (const float4*)(W_hh1 + j0 * Hn);
        const float4* p2o = (const float4*)(W_hh1 + (j0 + 1) * Hn);
        #pragma unroll
        for (int r = 0; r < 5; ++r) {
            *(float4*)&w0e[4*r] = p0e[r];  *(float4*)&w0o[4*r] = p0o[r];
            *(float4*)&w1e[4*r] = p1e[r];  *(float4*)&w1o[4*r] = p1o[r];
            *(float4*)&w2e[4*r] = p2e[r];  *(float4*)&w2o[4*r] = p2o[r];
        }
    }
    const float wih0e = W_ih0[j0],  wih0o = W_ih0[j0 + 1];
    const float b0e = b_ih0[j0]     + b_hh0[j0];
    const float b0o = b_ih0[j0 + 1] + b_hh0[j0 + 1];
    const float b1e = b_ih1[j0]     + b_hh1[j0];
    const float b1o = b_ih1[j0 + 1] + b_hh1[j0 + 1];

    // init state: h0 -> buf0; h1 -> buf0 AND buf1 (layer1 first reads buf1
    // at i=1, which i=0 does not write). 8B-aligned float2 ops (j0 even).
    {
        float2 h0i = *(const float2*)(hidden + bl * Hn + j0);
        float2 h1i = *(const float2*)(hidden + (long)Bsz * Hn + bl * Hn + j0);
        *(float2*)&h0s[0][g][j0] = h0i;
        *(float2*)&h1s[0][g][j0] = h1i;
        *(float2*)&h1s[1][g][j0] = h1i;
    }

    __syncthreads();                   // xs + init visible; globals done here
    float xt = xs[g][0];

    // iter i: layer0 computes h0[i] (i<T), layer1 computes h1[i-1] (i>0).
    // reads buf p=i&1 (h0[i-1], h1[i-2]); writes buf p^1.
    // NO global memory ops inside -> barrier drains only lgkmcnt.
    #pragma unroll 2
    for (int i = 0; i <= Tn; ++i) {
        const int p = i & 1, q = p ^ 1;

        float h0p[Hn], h1p[Hn];
        #pragma unroll
        for (int r = 0; r < 5; ++r) {   // conflict-free: 6 addrs, banks 20g+4r
            *(float4*)&h0p[4*r] = *(const float4*)&h0s[p][g][4*r];
            *(float4*)&h1p[4*r] = *(const float4*)&h1s[p][g][4*r];
        }

        // next x from LDS (padded rows -> conflict-free; off critical path)
        const int tn2 = (i + 1 < Tn) ? (i + 1) : (Tn - 1);
        const float xn = xs[g][tn2];

        // 6 independent 20-deep chains; e/o pairs share h operand (pk-able)
        float a0e = fmaf(xt, wih0e, b0e), a0o = fmaf(xt, wih0o, b0o);
        float a1e = b1e, a1o = b1o;
        float a2e = 0.f, a2o = 0.f;
        #pragma unroll
        for (int k = 0; k < Hn; ++k) {
            a0e = fmaf(w0e[k], h0p[k], a0e);
            a0o = fmaf(w0o[k], h0p[k], a0o);
            a1e = fmaf(w1e[k], h0p[k], a1e);
            a1o = fmaf(w1o[k], h0p[k], a1o);
            a2e = fmaf(w2e[k], h1p[k], a2e);
            a2o = fmaf(w2o[k], h1p[k], a2o);
        }

        if (i < Tn) {
            float2 n0 = make_float2(tanh_fast(a0e), tanh_fast(a0o));
            *(float2*)&h0s[q][g][j0] = n0;       // ds_write_b64
        }
        if (i > 0) {
            float2 n1 = make_float2(tanh_fast(a1e + a2e), tanh_fast(a1o + a2o));
            *(float2*)&h1s[q][g][j0] = n1;       // ds_write_b64
        }

        xt = xn;
        __syncthreads();   // single wave: lgkm-only drain
    }

    // final states: h0[511] written at i=511 -> buf0; h1[511] at i=512 -> buf1
    if (store_ok) {
        *(float2*)(out + Bsz + (long)b * Hn + j0) =
            *(const float2*)&h0s[0][g][j0];                       // new_hidden[0]
        *(float2*)(out + Bsz + (long)Bsz * Hn + (long)b * Hn + j0) =
            *(const float2*)&h1s[1][g][j0];                       // new_hidden[1]
        if (jj == 0) {                 // fc head: one lane per batch
            float acc = fc_b[0];
            #pragma unroll
            for (int k = 0; k < Hn; ++k)
                acc = fmaf(fc_w[k], h1s[1][g][k], acc);
            out[b] = acc;
        }
    }
}

extern "C" void kernel_launch(void* const* d_in, const int* in_sizes, int n_in,
                              void* d_out, int out_size, void* d_ws, size_t ws_size,
                              hipStream_t stream) {
    const float* x      = (const float*)d_in[0];
    const float* hidden = (const float*)d_in[1];
    const float* W_ih0  = (const float*)d_in[2];
    const float* W_hh0  = (const float*)d_in[3];
    const float* b_ih0  = (const float*)d_in[4];
    const float* b_hh0  = (const float*)d_in[5];
    const float* W_ih1  = (const float*)d_in[6];
    const float* W_hh1  = (const float*)d_in[7];
    const float* b_ih1  = (const float*)d_in[8];
    const float* b_hh1  = (const float*)d_in[9];
    const float* fc_w   = (const float*)d_in[10];
    const float* fc_b   = (const float*)d_in[11];

    const int nblocks = (Bsz + GB - 1) / GB;   // 683
    rnn2_fused<<<nblocks, NTHREADS, 0, stream>>>(
        x, hidden, W_ih0, W_hh0, b_ih0, b_hh0,
        W_ih1, W_hh1, b_ih1, b_hh1, fc_w, fc_b, (float*)d_out);
}

// Round 6
// 170.737 us; speedup vs baseline: 1.2176x; 1.2176x over previous
//
#include <hip/hip_runtime.h>

// 2-layer tanh RNN, fused, f32, single-wave blocks, NO BARRIERS AT ALL.
// B=4096 chains, T=512 steps, H=20.
// Key facts driving this version (R6):
//  - Wall time = 513 x per-wave critical path (independent chains; TLP
//    can't shrink it). So: minimize L.
//  - Single-wave workgroup => LDS ops execute in program order on the DS
//    pipe => ds_read after ds_write sees the data WITHOUT s_barrier.
//    __syncthreads() removed everywhere: no s_barrier, no lgkmcnt(0) full
//    drain, compiler free to software-pipeline reads behind writes.
//  - xs rows padded to 520 floats (R4's stride-512 x-read = 3-way bank
//    conflict, 1.4M events).
// Geometry: GB=3 batches/wave (R4's; shorter critical path than GB=6).
// Layer1 pipelined one step behind layer0.

#define Bsz 4096
#define Tn  512
#define Hn  20
#define GB  3
#define XPAD 520               // row stride: +8 banks/row, float4-aligned
#define NTHREADS 64

__device__ __forceinline__ float tanh_fast(float v) {
    // tanh(v) = 1 - 2/(exp(2v)+1); v_exp_f32 + v_rcp_f32.
    float e = __expf(2.0f * v);
    return 1.0f - 2.0f * __builtin_amdgcn_rcpf(e + 1.0f);
}

__global__ __launch_bounds__(NTHREADS)
void rnn2_fused(const float* __restrict__ x,        // [B,T,1]
                const float* __restrict__ hidden,   // [2,B,H]
                const float* __restrict__ W_ih0,    // [H,1]
                const float* __restrict__ W_hh0,    // [H,H]
                const float* __restrict__ b_ih0,    // [H]
                const float* __restrict__ b_hh0,    // [H]
                const float* __restrict__ W_ih1,    // [H,H]
                const float* __restrict__ W_hh1,    // [H,H]
                const float* __restrict__ b_ih1,    // [H]
                const float* __restrict__ b_hh1,    // [H]
                const float* __restrict__ fc_w,     // [1,H]
                const float* __restrict__ fc_b,     // [1]
                float* __restrict__ out)            // [B] ++ [2,B,H] flat
{
    const int tid = threadIdx.x;
    int g = tid / Hn;                  // 0..3
    int j = tid - g * Hn;              // 0..19 (0..3 for tid>=60)
    const bool lane_ok = (tid < GB * Hn);
    if (!lane_ok) g = GB - 1;          // lanes 60..63 duplicate batch 2
                                       // (same-addr same-value LDS writes: benign)

    const int  b        = blockIdx.x * GB + g;
    const bool b_ok     = (b < Bsz);
    const int  bl       = b_ok ? b : (Bsz - 1);
    const bool store_ok = lane_ok && b_ok;

    __shared__ float xs[GB][XPAD];     // 6.24 KB, padded rows
    __shared__ float h0s[2][GB][Hn];   // double-buffered hidden state
    __shared__ float h1s[2][GB][Hn];

    // stage ALL x up front (coalesced float4; clamp batch index; same-wave
    // in-order DS => later reads see these writes, no barrier needed)
    {
        const int bB = blockIdx.x * GB;
        #pragma unroll
        for (int r = 0; r < (GB * Tn) / (NTHREADS * 4); ++r) {  // 6 rounds
            const int c  = (r * NTHREADS + tid) * 4;
            const int gg = c >> 9;            // c / 512
            const int t  = c & (Tn - 1);      // c % 512
            const int bb = (bB + gg < Bsz) ? (bB + gg) : (Bsz - 1);
            float4 v = *(const float4*)(x + (long)bb * Tn + t);
            *(float4*)&xs[gg][t] = v;
        }
    }

    // per-thread weight rows (80B rows => 16B-aligned float4 loads)
    float whh0[Hn], wih1[Hn], whh1[Hn];
    {
        const float4* p0 = (const float4*)(W_hh0 + j * Hn);
        const float4* p1 = (const float4*)(W_ih1 + j * Hn);
        const float4* p2 = (const float4*)(W_hh1 + j * Hn);
        #pragma unroll
        for (int r = 0; r < 5; ++r) {
            *(float4*)&whh0[4*r] = p0[r];
            *(float4*)&wih1[4*r] = p1[r];
            *(float4*)&whh1[4*r] = p2[r];
        }
    }
    const float wih0  = W_ih0[j];
    const float bias0 = b_ih0[j] + b_hh0[j];
    const float bias1 = b_ih1[j] + b_hh1[j];

    // init: h0 -> buf0; h1 -> buf0 AND buf1 (layer1's first read is from
    // buf1 at i=1, which i=0 does not write)
    h0s[0][g][j] = hidden[bl * Hn + j];
    const float h1i = hidden[(long)Bsz * Hn + bl * Hn + j];
    h1s[0][g][j] = h1i;
    h1s[1][g][j] = h1i;

    // iter i: layer0 computes h0[i] (i<T), layer1 computes h1[i-1] (i>0).
    // reads buf p=i&1 (h0[i-1], h1[i-2]); writes buf p^1.
    // No barriers: single-wave in-order DS pipe provides write->read order;
    // compiler's conservative LDS aliasing keeps the backedge dependency.
    #pragma unroll 2
    for (int i = 0; i <= Tn; ++i) {
        const int p = i & 1, q = p ^ 1;

        float h0p[Hn], h1p[Hn];
        #pragma unroll
        for (int r = 0; r < 5; ++r) {   // broadcast b128, conflict-free
            *(float4*)&h0p[4*r] = *(const float4*)&h0s[p][g][4*r];
            *(float4*)&h1p[4*r] = *(const float4*)&h1s[p][g][4*r];
        }

        const float xt = xs[g][(i < Tn) ? i : (Tn - 1)];  // padded: no conflict

        // even/odd accumulator split (enables v_pk_fma_f32 packing)
        float a0x = fmaf(xt, wih0, bias0), a0y = 0.f;
        float a1x = bias1,                 a1y = 0.f;
        float a2x = 0.f,                   a2y = 0.f;
        #pragma unroll
        for (int k = 0; k < 10; ++k) {
            a0x = fmaf(whh0[2*k],   h0p[2*k],   a0x);
            a0y = fmaf(whh0[2*k+1], h0p[2*k+1], a0y);
            a1x = fmaf(wih1[2*k],   h0p[2*k],   a1x);
            a1y = fmaf(wih1[2*k+1], h0p[2*k+1], a1y);
            a2x = fmaf(whh1[2*k],   h1p[2*k],   a2x);
            a2y = fmaf(whh1[2*k+1], h1p[2*k+1], a2y);
        }

        const float n0 = tanh_fast(a0x + a0y);
        const float n1 = tanh_fast((a1x + a1y) + (a2x + a2y));

        if (i < Tn) h0s[q][g][j] = n0;
        if (i > 0)  h1s[q][g][j] = n1;
    }

    // final states: h0[511] written at i=511 -> buf0; h1[511] at i=512 -> buf1
    if (store_ok) {
        out[Bsz + b * Hn + j]                  = h0s[0][g][j];   // new_hidden[0]
        out[Bsz + (long)Bsz * Hn + b * Hn + j] = h1s[1][g][j];   // new_hidden[1]
        if (j == 0) {                                             // fc head
            float acc = fc_b[0];
            #pragma unroll
            for (int k = 0; k < Hn; ++k)
                acc = fmaf(fc_w[k], h1s[1][g][k], acc);
            out[b] = acc;
        }
    }
}

extern "C" void kernel_launch(void* const* d_in, const int* in_sizes, int n_in,
                              void* d_out, int out_size, void* d_ws, size_t ws_size,
                              hipStream_t stream) {
    const float* x      = (const float*)d_in[0];
    const float* hidden = (const float*)d_in[1];
    const float* W_ih0  = (const float*)d_in[2];
    const float* W_hh0  = (const float*)d_in[3];
    const float* b_ih0  = (const float*)d_in[4];
    const float* b_hh0  = (const float*)d_in[5];
    const float* W_ih1  = (const float*)d_in[6];
    const float* W_hh1  = (const float*)d_in[7];
    const float* b_ih1  = (const float*)d_in[8];
    const float* b_hh1  = (const float*)d_in[9];
    const float* fc_w   = (const float*)d_in[10];
    const float* fc_b   = (const float*)d_in[11];

    const int nblocks = (Bsz + GB - 1) / GB;   // 1366
    rnn2_fused<<<nblocks, NTHREADS, 0, stream>>>(
        x, hidden, W_ih0, W_hh0, b_ih0, b_hh0,
        W_ih1, W_hh1, b_ih1, b_hh1, fc_w, fc_b, (float*)d_out);
}